// Round 5
// baseline (1086.693 us; speedup 1.0000x reference)
//
#include <hip/hip_runtime.h>

// BinarizeLayer forward — two-kernel split:
//   bin_compute: one row/thread. Reads ONLY the cont half of x (the second
//     64B line of each 128B row -> exactly 33.5 MB, zero amplification),
//     runs the bit-exact soft_argmax_loss, packs k1|(k2<<4) per feature into
//     16 idx bytes/row (coalesced 16B/thread store, 8.4 MB), per-wave loss
//     partials. Small-memory, VALU-bound.
//   bin_expand: fill-like expansion. No LDS, tiny VGPR (-> 8 waves/SIMD),
//     2048x256 grid, 100 grid-stride steps; step s writes one contiguous
//     8.4 MB slab of out chip-wide (exactly the store pattern of the 6.3TB/s
//     fillBuffer). Onehot from idx bytes (L2-hot 8.4MB), disc chunks copied
//     from x's first 64B line per row.
//   Rationale: r3/r4 showed (a) nt stores -20us, (b) store fragmentation is
//   expensive, (c) compute/store phases already overlap chip-wide (interleave
//   made things worse). The fused kernel's store stream runs at ~2.5 TB/s
//   effective while 8-VGPR fill hits 6.3 TB/s; splitting gives the store
//   stream a fill-like kernel (max occupancy, no exp/f64/LDS in the wave).
//   Fallback: if ws_size < idx buffer + partials, run the verified r0 fused
//   kernel unchanged (891.8 us).
//   Numerics: soft_argmax_loss verbatim; lacc order (f asc, K1 then K2)
//   unchanged; disc passthrough copies x bits; onehot values identical.

constexpr int kB      = 524288;
constexpr int kF      = 16;
constexpr int kK1     = 16;
constexpr int kK2     = 8;
constexpr int kRowIn  = 32;    // DISC + F
constexpr int kRowOut = 400;   // DISC + F*K1 + F*K2
constexpr float kEps  = 0.001f;
constexpr int kTPB    = 256;
constexpr int kGrid   = kB / kTPB;     // 2048 blocks
constexpr int kC4     = kRowOut / 4;   // 100 float4 chunks per row
constexpr int kXStride = 33;           // LDS row stride (fallback kernel)
constexpr int kWPB    = kTPB / 64;     // waves per block (4)

constexpr size_t kIdxBytes = (size_t)kB * kF;                 // 8,388,608
constexpr size_t kPartOff  = kIdxBytes;                        // 8-aligned
constexpr size_t kWsNeed   = kIdxBytes + (size_t)kGrid * kWPB * sizeof(double);

typedef float f32x4 __attribute__((ext_vector_type(4)));
typedef unsigned long long u64x2 __attribute__((ext_vector_type(2)));

template <int K>
__device__ __forceinline__ int soft_argmax_loss(const float* __restrict__ dd,
                                                double& lacc)
{
#pragma clang fp contract(off)
    // ---- loss term: sum_k d * softmax(-d). Fast exp: output is threshold-checked.
    float se = 0.f, sde = 0.f;
#pragma unroll
    for (int k = 0; k < K; ++k) {
        float e = __expf(-dd[k]);
        se += e; sde += dd[k] * e;
    }
    lacc += (double)(sde / se);

    // ---- argmax(softmax(-100*d)) fast path: first-occurrence argmax of z ----
    float z[K];
#pragma unroll
    for (int k = 0; k < K; ++k) z[k] = -100.0f * dd[k];
    float m = z[0]; int kmax = 0;
#pragma unroll
    for (int k = 1; k < K; ++k) {
        if (z[k] > m) { m = z[k]; kmax = k; }
    }

    // argmax can only move to an EARLIER index whose p rounds equal to p_kmax;
    // that needs z_j >= m - ~1.2e-7. Conservative guard takes the exact
    // replication path (exec-masked, ~never).
    bool cand = false;
#pragma unroll
    for (int k = 0; k < K; ++k)
        cand |= (k < kmax) & (z[k] >= m - 2.4e-7f);
    if (cand) {
        float e2[K]; float ss = 0.f;
        for (int k = 0; k < K; ++k) { e2[k] = expf(z[k] - m); ss += e2[k]; }
        int km = 0; float pmax = e2[0] / ss;
        for (int k = 1; k < K; ++k) {
            float p = e2[k] / ss;
            if (p > pmax) { pmax = p; km = k; }
        }
        kmax = km;
    }
    return kmax;
}

__device__ __forceinline__ f32x4 onehot4(unsigned k, unsigned q)
{
    f32x4 o;
    o.x = (k == q + 0u) ? 1.f : 0.f;
    o.y = (k == q + 1u) ? 1.f : 0.f;
    o.z = (k == q + 2u) ? 1.f : 0.f;
    o.w = (k == q + 3u) ? 1.f : 0.f;
    return o;
}

// ---------------------------------------------------------------- compute ---
__global__ __launch_bounds__(kTPB) void bin_compute(
    const float* __restrict__ x,
    const float* __restrict__ interval,
    const float* __restrict__ interval2,
    const float* __restrict__ i_min,
    unsigned long long* __restrict__ idxbuf,   // kB rows x 16 bytes (as 2x u64)
    double* __restrict__ partial)              // kGrid*kWPB per-wave partials
{
#pragma clang fp contract(off)
    __shared__ float sC1[kF][kK1];
    __shared__ float sC2[kF][kK2];

    const int tid = threadIdx.x;
    const int w   = tid >> 6;
    const int l   = tid & 63;

    if (tid < kF) {
        const float base = i_min[tid];
        float run = 0.f;
        for (int k = 0; k < kK1; ++k) {
            run += fmaxf(interval[tid * kK1 + k], kEps);
            sC1[tid][k] = base + run;
        }
        run = 0.f;
        for (int k = 0; k < kK2; ++k) {
            run += fmaxf(interval2[tid * kK2 + k], kEps);
            sC2[tid][k] = base + run;
        }
    }
    __syncthreads();

    const long long row = (long long)blockIdx.x * kTPB + tid;
    const float* __restrict__ xr = x + row * kRowIn + 16;   // cont half-line

    double lacc = 0.0;
    unsigned long long lo = 0ull, hi = 0ull;

#pragma unroll 1
    for (int f = 0; f < kF; ++f) {
        const float c = xr[f];    // scalar load; line L2-resident after f=0

        float dd1[kK1];
#pragma unroll
        for (int k = 0; k < kK1; ++k) { float t = c - sC1[f][k]; dd1[k] = t * t; }
        int k1 = soft_argmax_loss<kK1>(dd1, lacc);

        float dd2[kK2];
#pragma unroll
        for (int k = 0; k < kK2; ++k) { float t = c - sC2[f][k]; dd2[k] = t * t; }
        int k2 = soft_argmax_loss<kK2>(dd2, lacc);

        const unsigned long long byte = (unsigned long long)(k1 | (k2 << 4));
        if (f < 8) lo |= byte << (8 * f);
        else       hi |= byte << (8 * (f - 8));
    }

    // idx store: 16B per thread, fully coalesced
    u64x2 pk; pk.x = lo; pk.y = hi;
    *reinterpret_cast<u64x2*>(&idxbuf[row * 2]) = pk;

    // loss: wave shuffle-reduce -> one per-wave partial (no atomics/barriers)
#pragma unroll
    for (int off = 32; off > 0; off >>= 1) lacc += __shfl_down(lacc, off);
    if (l == 0) partial[(long long)blockIdx.x * kWPB + w] = lacc;
}

// ---------------------------------------------------------------- expand ----
__global__ __launch_bounds__(kTPB) void bin_expand(
    const float* __restrict__ x,
    const unsigned char* __restrict__ ib,      // kB x 16 idx bytes
    float* __restrict__ out)
{
    const unsigned t0 = blockIdx.x * kTPB + threadIdx.x;   // 0..524287
    f32x4* __restrict__ o4 = (f32x4*)out;

#pragma unroll 1
    for (int s = 0; s < kC4; ++s) {
        const unsigned chunk = (unsigned)s * (unsigned)kB + t0;  // < 52.4M
        const unsigned r = chunk / 100u;
        const unsigned c = chunk - r * 100u;
        f32x4 o;
        if (c < 4u) {
            // disc passthrough: first 64B line of x row r (bit copy)
            o = *reinterpret_cast<const f32x4*>(x + (size_t)r * kRowIn + c * 4u);
        } else {
            const unsigned u = c - 4u;
            unsigned f, q, k;
            if (u < 64u) { f = u >> 2; q = (u & 3u) * 4u; k = ib[r * 16u + f] & 15u; }
            else { const unsigned uu = u - 64u; f = uu >> 1; q = (uu & 1u) * 4u;
                   k = (unsigned)(ib[r * 16u + f]) >> 4; }
            o = onehot4(k, q);
        }
        o4[chunk] = o;   // step s = one contiguous 8.4 MB slab chip-wide
    }
}

// ---------------------------------------------------- r0 fused (fallback) ---
__global__ __launch_bounds__(kTPB) void binlayer_main(
    const float* __restrict__ x,
    const float* __restrict__ interval,
    const float* __restrict__ interval2,
    const float* __restrict__ i_min,
    float* __restrict__ out,
    double* __restrict__ partial)
{
#pragma clang fp contract(off)
    __shared__ float sC1[kF][kK1];
    __shared__ float sC2[kF][kK2];
    __shared__ float sX[kTPB * kXStride];
    __shared__ unsigned char sIdx[kTPB * kF];
    __shared__ double sL[kTPB / 64];

    const int tid = threadIdx.x;

    if (tid < kF) {
        const float base = i_min[tid];
        float run = 0.f;
        for (int k = 0; k < kK1; ++k) {
            run += fmaxf(interval[tid * kK1 + k], kEps);
            sC1[tid][k] = base + run;
        }
        run = 0.f;
        for (int k = 0; k < kK2; ++k) {
            run += fmaxf(interval2[tid * kK2 + k], kEps);
            sC2[tid][k] = base + run;
        }
    }

    const long long rowBase = (long long)blockIdx.x * kTPB;

    const float4* __restrict__ xin4 = (const float4*)(x + rowBase * kRowIn);
#pragma unroll
    for (int i = 0; i < (kTPB * kRowIn / 4) / kTPB; ++i) {
        int flat = i * kTPB + tid;
        float4 v = xin4[flat];
        int r = flat >> 3, c4 = flat & 7;
        float* p = &sX[r * kXStride + c4 * 4];
        p[0] = v.x; p[1] = v.y; p[2] = v.z; p[3] = v.w;
    }
    __syncthreads();

    double lacc = 0.0;
    const float* __restrict__ myc = &sX[tid * kXStride + 16];

#pragma unroll 1
    for (int f = 0; f < kF; ++f) {
        const float c = myc[f];

        float dd1[kK1];
#pragma unroll
        for (int k = 0; k < kK1; ++k) { float t = c - sC1[f][k]; dd1[k] = t * t; }
        int k1 = soft_argmax_loss<kK1>(dd1, lacc);

        float dd2[kK2];
#pragma unroll
        for (int k = 0; k < kK2; ++k) { float t = c - sC2[f][k]; dd2[k] = t * t; }
        int k2 = soft_argmax_loss<kK2>(dd2, lacc);

        sIdx[tid * kF + f] = (unsigned char)(k1 | (k2 << 4));
    }

#pragma unroll
    for (int off = 32; off > 0; off >>= 1) lacc += __shfl_down(lacc, off);
    if ((tid & 63) == 0) sL[tid >> 6] = lacc;

    __syncthreads();

    if (tid == 0) partial[blockIdx.x] = sL[0] + sL[1] + sL[2] + sL[3];

    float4* __restrict__ o4 = (float4*)(out + rowBase * kRowOut);
#pragma unroll 1
    for (int i = 0; i < kC4; ++i) {
        unsigned idx = (unsigned)(i * kTPB + tid);
        unsigned r = idx / 100u;
        unsigned c = idx - r * 100u;
        float4 o;
        if (c < 4u) {
            const float* p = &sX[r * kXStride + c * 4u];
            o.x = p[0]; o.y = p[1]; o.z = p[2]; o.w = p[3];
        } else if (c < 68u) {
            unsigned u = c - 4u, f = u >> 2, q = (u & 3u) * 4u;
            unsigned k = sIdx[r * kF + f] & 15u;
            o.x = (k == q + 0u) ? 1.f : 0.f;
            o.y = (k == q + 1u) ? 1.f : 0.f;
            o.z = (k == q + 2u) ? 1.f : 0.f;
            o.w = (k == q + 3u) ? 1.f : 0.f;
        } else {
            unsigned u = c - 68u, f = u >> 1, q = (u & 1u) * 4u;
            unsigned k = (unsigned)(sIdx[r * kF + f]) >> 4;
            o.x = (k == q + 0u) ? 1.f : 0.f;
            o.y = (k == q + 1u) ? 1.f : 0.f;
            o.z = (k == q + 2u) ? 1.f : 0.f;
            o.w = (k == q + 3u) ? 1.f : 0.f;
        }
        o4[idx] = o;
    }
}

__global__ __launch_bounds__(256) void binlayer_finalize(
    const double* __restrict__ partial,
    float* __restrict__ out,
    int n)
{
    __shared__ double sL[4];
    const int tid = threadIdx.x;
    double s = 0.0;
    for (int i = tid; i < n; i += 256)
        s += partial[i];
#pragma unroll
    for (int off = 32; off > 0; off >>= 1) s += __shfl_down(s, off);
    if ((tid & 63) == 0) sL[tid >> 6] = s;
    __syncthreads();
    if (tid == 0)
        out[(long long)kB * kRowOut] =
            (float)((sL[0] + sL[1] + sL[2] + sL[3]) * (1.0 / (double)kB));
}

extern "C" void kernel_launch(void* const* d_in, const int* in_sizes, int n_in,
                              void* d_out, int out_size, void* d_ws, size_t ws_size,
                              hipStream_t stream)
{
    const float* x    = (const float*)d_in[0];
    const float* itv1 = (const float*)d_in[1];
    const float* itv2 = (const float*)d_in[2];
    const float* imin = (const float*)d_in[3];
    float* out = (float*)d_out;

    if (ws_size >= kWsNeed) {
        unsigned long long* idxbuf = (unsigned long long*)d_ws;
        double* partial = (double*)((char*)d_ws + kPartOff);
        bin_compute<<<kGrid, kTPB, 0, stream>>>(x, itv1, itv2, imin, idxbuf, partial);
        bin_expand<<<kGrid, kTPB, 0, stream>>>(x, (const unsigned char*)d_ws, out);
        binlayer_finalize<<<1, 256, 0, stream>>>(partial, out, kGrid * kWPB);
    } else {
        // fallback: verified r0 fused kernel (needs only 16 KB ws)
        double* partial = (double*)d_ws;
        binlayer_main<<<kGrid, kTPB, 0, stream>>>(x, itv1, itv2, imin, out, partial);
        binlayer_finalize<<<1, 256, 0, stream>>>(partial, out, kGrid);
    }
}

// Round 7
// 892.890 us; speedup vs baseline: 1.2171x; 1.2171x over previous
//
#include <hip/hip_runtime.h>

// BinarizeLayer forward:
//   phase 1: coalesced float4 tile load (256 rows x 32 f32) -> LDS (stride 33)
//   phase 2: one row per thread.
//     loss: sum_k d*softmax(-d) via __expf (threshold-checked output, rel err ~1e-6)
//     argmax(softmax(-100 d)) == first-occurrence argmax(z), z=-100d, UNLESS an
//       earlier index ties after exp/divide rounding -- requires z_j >= m - ~2^-23.
//       Conservative guard (2.4e-7) takes the exact expf+IEEE-div replication only
//       then (exec-masked, ~never in practice). Bit-faithful to fp32 numpy ref.
//   phase 3: 100 fully-coalesced float4 stores per block (contiguous 400 KB).
//   loss: block partial sums -> d_ws (NO atomics: fp64 atomicAdd is a CAS retry
//   loop on gfx950 without unsafe-fp-atomics; 8192-way contention was pathological),
//   finalize kernel reduces 2048 partials.
//
// Session post-mortem (rounds 3-5): four structural alternatives were measured
// WORSE than this shape -- (a) removing the mid-kernel barrier (+20us with nt
// stores; nt alone ~-20), (b) interleaving stores with compute at feature-group
// granularity (+111us: fragmented store bursts cost more than any overlap win),
// (c) splitting into a compute kernel + fill-shaped expand kernel (+195us).
// The {bulk load -> barrier -> compute -> barrier -> bulk store} structure with
// plain cached stores is the empirical optimum; the dominant timed-region costs
// (533us harness re-poison fill at 78% HBM peak + harness restore dispatches)
// are outside kernel control.

constexpr int kB      = 524288;
constexpr int kF      = 16;
constexpr int kK1     = 16;
constexpr int kK2     = 8;
constexpr int kRowIn  = 32;    // DISC + F
constexpr int kRowOut = 400;   // DISC + F*K1 + F*K2
constexpr float kEps  = 0.001f;
constexpr int kTPB    = 256;   // threads per block == rows per block
constexpr int kGrid   = kB / kTPB;     // 2048 blocks
constexpr int kC4     = kRowOut / 4;   // 100 float4 chunks per row
constexpr int kXStride = 33;   // LDS row stride in floats (conflict-free)

template <int K>
__device__ __forceinline__ int soft_argmax_loss(const float* __restrict__ dd,
                                                double& lacc)
{
#pragma clang fp contract(off)
    // ---- loss term: sum_k d * softmax(-d). Fast exp: output is threshold-checked.
    float se = 0.f, sde = 0.f;
#pragma unroll
    for (int k = 0; k < K; ++k) {
        float e = __expf(-dd[k]);
        se += e; sde += dd[k] * e;
    }
    lacc += (double)(sde / se);

    // ---- argmax(softmax(-100*d)) fast path: first-occurrence argmax of z ----
    float z[K];
#pragma unroll
    for (int k = 0; k < K; ++k) z[k] = -100.0f * dd[k];
    float m = z[0]; int kmax = 0;
#pragma unroll
    for (int k = 1; k < K; ++k) {
        if (z[k] > m) { m = z[k]; kmax = k; }
    }

    // softmax is a monotone-nondecreasing transform of z, so argmax can only
    // move to an EARLIER index j<kmax whose p_j rounds equal to p_kmax. That
    // needs exp(z_j-m) to round within ~1 ulp of exp(0)=1, i.e. z_j-m >= ~-1.2e-7.
    // (For large |m|, distinct z differ by >> that, so only exact ties pass.)
    bool cand = false;
#pragma unroll
    for (int k = 0; k < K; ++k)
        cand |= (k < kmax) & (z[k] >= m - 2.4e-7f);
    if (cand) {
        // exact replication of the fp32 reference: accurate expf, ordered sum,
        // IEEE divides, strict-> first-occurrence scan.
        float e2[K]; float ss = 0.f;
        for (int k = 0; k < K; ++k) { e2[k] = expf(z[k] - m); ss += e2[k]; }
        int km = 0; float pmax = e2[0] / ss;
        for (int k = 1; k < K; ++k) {
            float p = e2[k] / ss;
            if (p > pmax) { pmax = p; km = k; }
        }
        kmax = km;
    }
    return kmax;
}

__global__ __launch_bounds__(kTPB) void binlayer_main(
    const float* __restrict__ x,
    const float* __restrict__ interval,
    const float* __restrict__ interval2,
    const float* __restrict__ i_min,
    float* __restrict__ out,
    double* __restrict__ partial)
{
#pragma clang fp contract(off)
    __shared__ float sC1[kF][kK1];
    __shared__ float sC2[kF][kK2];
    __shared__ float sX[kTPB * kXStride];
    __shared__ unsigned char sIdx[kTPB * kF];
    __shared__ double sL[kTPB / 64];

    const int tid = threadIdx.x;

    // centers: i_min + fp32 cumsum of max(interval, eps), in k order
    if (tid < kF) {
        const float base = i_min[tid];
        float run = 0.f;
        for (int k = 0; k < kK1; ++k) {
            run += fmaxf(interval[tid * kK1 + k], kEps);
            sC1[tid][k] = base + run;
        }
        run = 0.f;
        for (int k = 0; k < kK2; ++k) {
            run += fmaxf(interval2[tid * kK2 + k], kEps);
            sC2[tid][k] = base + run;
        }
    }

    const long long rowBase = (long long)blockIdx.x * kTPB;

    // ---------------- phase 1: coalesced tile load ----------------
    const float4* __restrict__ xin4 = (const float4*)(x + rowBase * kRowIn);
#pragma unroll
    for (int i = 0; i < (kTPB * kRowIn / 4) / kTPB; ++i) {   // 8 iters
        int flat = i * kTPB + tid;                 // 0..2047 float4s
        float4 v = xin4[flat];
        int r = flat >> 3, c4 = flat & 7;
        float* p = &sX[r * kXStride + c4 * 4];
        p[0] = v.x; p[1] = v.y; p[2] = v.z; p[3] = v.w;
    }
    __syncthreads();

    // ---------------- phase 2: one row per thread ----------------
    double lacc = 0.0;
    const float* __restrict__ myc = &sX[tid * kXStride + 16];

#pragma unroll 1
    for (int f = 0; f < kF; ++f) {
        const float c = myc[f];

        float dd1[kK1];
#pragma unroll
        for (int k = 0; k < kK1; ++k) { float t = c - sC1[f][k]; dd1[k] = t * t; }
        int k1 = soft_argmax_loss<kK1>(dd1, lacc);

        float dd2[kK2];
#pragma unroll
        for (int k = 0; k < kK2; ++k) { float t = c - sC2[f][k]; dd2[k] = t * t; }
        int k2 = soft_argmax_loss<kK2>(dd2, lacc);

        sIdx[tid * kF + f] = (unsigned char)(k1 | (k2 << 4));
    }

    // loss: wave shuffle-reduce -> LDS -> one plain store per block (no atomics)
#pragma unroll
    for (int off = 32; off > 0; off >>= 1) lacc += __shfl_down(lacc, off);
    if ((tid & 63) == 0) sL[tid >> 6] = lacc;

    __syncthreads();   // covers sIdx visibility for phase 3 and sL for tid 0

    if (tid == 0) partial[blockIdx.x] = sL[0] + sL[1] + sL[2] + sL[3];

    // ---------------- phase 3: fully coalesced stores ----------------
    float4* __restrict__ o4 = (float4*)(out + rowBase * kRowOut);
#pragma unroll 1
    for (int i = 0; i < kC4; ++i) {                  // 100 iters
        unsigned idx = (unsigned)(i * kTPB + tid);   // 0..25599
        unsigned r = idx / 100u;                     // row in tile
        unsigned c = idx - r * 100u;                 // float4 chunk in row
        float4 o;
        if (c < 4u) {
            const float* p = &sX[r * kXStride + c * 4u];
            o.x = p[0]; o.y = p[1]; o.z = p[2]; o.w = p[3];
        } else if (c < 68u) {
            unsigned u = c - 4u, f = u >> 2, q = (u & 3u) * 4u;
            unsigned k = sIdx[r * kF + f] & 15u;
            o.x = (k == q + 0u) ? 1.f : 0.f;
            o.y = (k == q + 1u) ? 1.f : 0.f;
            o.z = (k == q + 2u) ? 1.f : 0.f;
            o.w = (k == q + 3u) ? 1.f : 0.f;
        } else {
            unsigned u = c - 68u, f = u >> 1, q = (u & 1u) * 4u;
            unsigned k = (unsigned)(sIdx[r * kF + f]) >> 4;
            o.x = (k == q + 0u) ? 1.f : 0.f;
            o.y = (k == q + 1u) ? 1.f : 0.f;
            o.z = (k == q + 2u) ? 1.f : 0.f;
            o.w = (k == q + 3u) ? 1.f : 0.f;
        }
        o4[idx] = o;
    }
}

__global__ __launch_bounds__(256) void binlayer_finalize(
    const double* __restrict__ partial,
    float* __restrict__ out)
{
    __shared__ double sL[4];
    const int tid = threadIdx.x;
    double s = 0.0;
#pragma unroll
    for (int i = 0; i < kGrid / 256; ++i)       // 8 values each
        s += partial[i * 256 + tid];
#pragma unroll
    for (int off = 32; off > 0; off >>= 1) s += __shfl_down(s, off);
    if ((tid & 63) == 0) sL[tid >> 6] = s;
    __syncthreads();
    if (tid == 0)
        out[(long long)kB * kRowOut] =
            (float)((sL[0] + sL[1] + sL[2] + sL[3]) * (1.0 / (double)kB));
}

extern "C" void kernel_launch(void* const* d_in, const int* in_sizes, int n_in,
                              void* d_out, int out_size, void* d_ws, size_t ws_size,
                              hipStream_t stream)
{
    const float* x    = (const float*)d_in[0];
    const float* itv1 = (const float*)d_in[1];
    const float* itv2 = (const float*)d_in[2];
    const float* imin = (const float*)d_in[3];
    float* out = (float*)d_out;
    double* partial = (double*)d_ws;   // kGrid doubles = 16 KB

    binlayer_main<<<kGrid, kTPB, 0, stream>>>(x, itv1, itv2, imin, out, partial);
    binlayer_finalize<<<1, 256, 0, stream>>>(partial, out);
}